// Round 3
// baseline (290.965 us; speedup 1.0000x reference)
//
#include <hip/hip_runtime.h>
#include <math.h>

// Chamfer loss, B=4, C=3, Np=Ng=8192, fp32.
// Round 7: R0 sweep body (LDS ytile broadcast, RX=8 => 32 packed-FMA issue
// cycles per 32B ds_read pair) + plain-store publish (no atomics: R1 showed
// ~6ns/atomicMin, ~13us at R0 scale) + full subscription (YSPL=64 -> 2048 wgs
// = 8192 waves, launch_bounds(256,8) pins VGPR<=64) + stream-ordered reduce.
// R2 lesson: y-broadcast via uniform GLOBAL loads at RX=2 is latency-bound
// (80us); LDS + high RX is the right intensity structure.
// ws gates: >=16.8MB primary (YSPL=64), >=8.4MB secondary (YSPL=32),
// else R0 fused fallback (257KB).

#define B_       4
#define N_       8192
#define THREADS  256
#define RX       8
#define XB       (THREADS * RX)        // 2048 x-points per workgroup
#define XBLKS    (N_ / XB)             // 4
#define NPB      (2 * B_)              // 8 (pass,b) slabs

typedef float v2f __attribute__((ext_vector_type(2)));

__device__ __forceinline__ v2f pk_fma(v2f a, v2f b, v2f c) {
    v2f d;
    asm("v_pk_fma_f32 %0, %1, %2, %3" : "=v"(d) : "v"(a), "v"(b), "v"(c));
    return d;
}

// ---------------- primary path: sweep + reduce, atomic-free ----------------
// partial layout: [pb][ysplit][x:8192] floats.

template<int YSPL>
__global__ __launch_bounds__(THREADS, 8)
void chamfer_sweep_t(const float* __restrict__ P, const float* __restrict__ G,
                     float* __restrict__ partial)
{
    constexpr int YCHUNK = N_ / YSPL;
    __shared__ float4 ytile[2 * (YCHUNK / 2)];   // pair-interleaved records

    const int t      = threadIdx.x;
    const int xblk   = blockIdx.x;     // 0..XBLKS-1
    const int ysplit = blockIdx.y;     // 0..YSPL-1
    const int bz     = blockIdx.z;     // 0..7
    const int pass   = bz >> 2;        // 0: X=predict, 1: X=gt
    const int b      = bz & 3;

    const float* Xb = (pass ? G : P) + (size_t)b * 3 * N_;
    const float* Yb = (pass ? P : G) + (size_t)b * 3 * N_;

    // Stage y-pairs: slot 2*jj = (gx0,gx1,gy0,gy1), 2*jj+1 = (gz0,gz1,g2_0,g2_1)
    const int ybase = ysplit * YCHUNK;
    if (t < YCHUNK / 2) {
        const int n0 = ybase + 2 * t;
        float2 x01 = *(const float2*)&Yb[n0];
        float2 y01 = *(const float2*)&Yb[N_ + n0];
        float2 z01 = *(const float2*)&Yb[2 * N_ + n0];
        float w0 = fmaf(x01.x, x01.x, fmaf(y01.x, y01.x, z01.x * z01.x));
        float w1 = fmaf(x01.y, x01.y, fmaf(y01.y, y01.y, z01.y * z01.y));
        ytile[2 * t]     = make_float4(x01.x, x01.y, y01.x, y01.y);
        ytile[2 * t + 1] = make_float4(z01.x, z01.y, w0, w1);
    }

    // RX x-points per thread; -2*coord duplicated into both float2 halves.
    const int xbase = xblk * XB;
    v2f m2x2[RX], m2y2[RX], m2z2[RX];
    float p2[RX], mn[RX];
#pragma unroll
    for (int r = 0; r < RX; ++r) {
        const int n = xbase + r * THREADS + t;
        float px = Xb[n];
        float py = Xb[N_ + n];
        float pz = Xb[2 * N_ + n];
        p2[r]   = fmaf(px, px, fmaf(py, py, pz * pz));
        float ax = -2.0f * px, ay = -2.0f * py, az = -2.0f * pz;
        m2x2[r] = (v2f){ax, ax};
        m2y2[r] = (v2f){ay, ay};
        m2z2[r] = (v2f){az, az};
        mn[r]   = 3.4e38f;
    }
    __syncthreads();

    // Sweep: per y-pair, per r: s = g2 - 2p.g for both y's (3 pk_fma),
    // then one min3 folds both halves into mn[r].
#pragma unroll 2
    for (int jj = 0; jj < YCHUNK / 2; ++jj) {
        float4 a4 = ytile[2 * jj];       // (gx0,gx1,gy0,gy1)
        float4 b4 = ytile[2 * jj + 1];   // (gz0,gz1,g2_0,g2_1)
        v2f gx2 = (v2f){a4.x, a4.y};
        v2f gy2 = (v2f){a4.z, a4.w};
        v2f gz2 = (v2f){b4.x, b4.y};
        v2f gw2 = (v2f){b4.z, b4.w};
#pragma unroll
        for (int r = 0; r < RX; ++r) {
            v2f s = pk_fma(m2z2[r], gz2, gw2);
            s = pk_fma(m2y2[r], gy2, s);
            s = pk_fma(m2x2[r], gx2, s);
            mn[r] = fminf(fminf(mn[r], s.x), s.y);   // -> v_min3_f32
        }
    }

    // Plain coalesced stores of clamped partial d2 (disjoint slots per wg).
    float* pout = partial + ((size_t)bz * YSPL + ysplit) * N_ + xbase;
#pragma unroll
    for (int r = 0; r < RX; ++r)
        pout[r * THREADS + t] = fmaxf(mn[r] + p2[r], 1e-12f);
}

// K2: per x-slot: min over YSPL partials, sqrt, block tree-sum.
template<int YSPL>
__global__ __launch_bounds__(THREADS)
void chamfer_reduce1_t(const float* __restrict__ partial,
                       float* __restrict__ gsum2)
{
    __shared__ float red[THREADS];
    const int g  = blockIdx.x * THREADS + threadIdx.x;   // [0, 65536)
    const int pb = g >> 13;
    const int x  = g & 8191;
    const float* p = partial + (size_t)pb * YSPL * N_ + x;
    float m = p[0];
#pragma unroll
    for (int ys = 1; ys < YSPL; ++ys)
        m = fminf(m, p[(size_t)ys * N_]);
    red[threadIdx.x] = sqrtf(m);
    __syncthreads();
    for (int off = 128; off > 0; off >>= 1) {
        if (threadIdx.x < off) red[threadIdx.x] += red[threadIdx.x + off];
        __syncthreads();
    }
    if (threadIdx.x == 0) gsum2[blockIdx.x] = red[0];
}

// K3: deterministic final sum of 256 block sums.
__global__ __launch_bounds__(THREADS)
void chamfer_final_kernel(const float* __restrict__ gsum2, float* __restrict__ out)
{
    __shared__ float red[THREADS];
    red[threadIdx.x] = gsum2[threadIdx.x];
    __syncthreads();
    for (int off = 128; off > 0; off >>= 1) {
        if (threadIdx.x < off) red[threadIdx.x] += red[threadIdx.x + off];
        __syncthreads();
    }
    if (threadIdx.x == 0) out[0] = red[0] * (1.0f / 65536.0f);   // denom = B*(Ng+Np)
}

// ---------------- fallback path (known-good R0, 257KB ws) ----------------
#define LRX      8
#define LXB      (THREADS * LRX)       // 2048
#define LXBLKS   (N_ / LXB)            // 4
#define LYSPL    32
#define LYCHUNK  (N_ / LYSPL)          // 256
#define LNGROUPS (2 * B_ * LXBLKS)     // 32
#define POISON   0xAAAAAAAAu

__global__ __launch_bounds__(THREADS)
void chamfer_fused_kernel(const float* __restrict__ P, const float* __restrict__ G,
                          unsigned* __restrict__ mins, unsigned* __restrict__ gcnt,
                          unsigned* __restrict__ fcnt, float* __restrict__ gsum,
                          float* __restrict__ out)
{
    __shared__ float4 ytile[2 * (LYCHUNK / 2)];
    __shared__ float red[THREADS];
    __shared__ unsigned s_ticket;

    const int t      = threadIdx.x;
    const int xblk   = blockIdx.x;
    const int ysplit = blockIdx.y;
    const int bz     = blockIdx.z;
    const int pass   = bz >> 2;
    const int b      = bz & 3;
    const int gid    = bz * LXBLKS + xblk;

    const float* Xb = (pass ? G : P) + (size_t)b * 3 * N_;
    const float* Yb = (pass ? P : G) + (size_t)b * 3 * N_;

    const int ybase = ysplit * LYCHUNK;
    if (t < LYCHUNK / 2) {
        const int n0 = ybase + 2 * t;
        float2 x01 = *(const float2*)&Yb[n0];
        float2 y01 = *(const float2*)&Yb[N_ + n0];
        float2 z01 = *(const float2*)&Yb[2 * N_ + n0];
        float w0 = fmaf(x01.x, x01.x, fmaf(y01.x, y01.x, z01.x * z01.x));
        float w1 = fmaf(x01.y, x01.y, fmaf(y01.y, y01.y, z01.y * z01.y));
        ytile[2 * t]     = make_float4(x01.x, x01.y, y01.x, y01.y);
        ytile[2 * t + 1] = make_float4(z01.x, z01.y, w0, w1);
    }

    const int xbase = xblk * LXB;
    v2f m2x2[LRX], m2y2[LRX], m2z2[LRX];
    float p2[LRX], mn[LRX];
#pragma unroll
    for (int r = 0; r < LRX; ++r) {
        const int n = xbase + r * THREADS + t;
        float px = Xb[n];
        float py = Xb[N_ + n];
        float pz = Xb[2 * N_ + n];
        p2[r]   = fmaf(px, px, fmaf(py, py, pz * pz));
        float ax = -2.0f * px, ay = -2.0f * py, az = -2.0f * pz;
        m2x2[r] = (v2f){ax, ax};
        m2y2[r] = (v2f){ay, ay};
        m2z2[r] = (v2f){az, az};
        mn[r]   = 3.4e38f;
    }
    __syncthreads();

#pragma unroll 2
    for (int jj = 0; jj < LYCHUNK / 2; ++jj) {
        float4 a4 = ytile[2 * jj];
        float4 b4 = ytile[2 * jj + 1];
        v2f gx2 = (v2f){a4.x, a4.y};
        v2f gy2 = (v2f){a4.z, a4.w};
        v2f gz2 = (v2f){b4.x, b4.y};
        v2f gw2 = (v2f){b4.z, b4.w};
#pragma unroll
        for (int r = 0; r < LRX; ++r) {
            v2f s = pk_fma(m2z2[r], gz2, gw2);
            s = pk_fma(m2y2[r], gy2, s);
            s = pk_fma(m2x2[r], gx2, s);
            mn[r] = fminf(fminf(mn[r], s.x), s.y);
        }
    }

    unsigned* mybase = mins + (size_t)(pass * B_ + b) * N_ + xbase;
#pragma unroll
    for (int r = 0; r < LRX; ++r) {
        float v = fmaxf(mn[r] + p2[r], 1e-12f);
        atomicMin(&mybase[r * THREADS + t], __float_as_uint(v));
    }

    __syncthreads();
    if (t == 0) {
        __threadfence();
        s_ticket = atomicAdd(&gcnt[gid], 1u);
    }
    __syncthreads();
    if (s_ticket != POISON + (unsigned)(LYSPL - 1)) return;

    __threadfence();
    const uint4* vmin = (const uint4*)(mins + (size_t)(pass * B_ + b) * N_ + xbase);
    uint4 q0 = vmin[t];
    uint4 q1 = vmin[THREADS + t];
    float a = sqrtf(__uint_as_float(q0.x)) + sqrtf(__uint_as_float(q0.y))
            + sqrtf(__uint_as_float(q0.z)) + sqrtf(__uint_as_float(q0.w))
            + sqrtf(__uint_as_float(q1.x)) + sqrtf(__uint_as_float(q1.y))
            + sqrtf(__uint_as_float(q1.z)) + sqrtf(__uint_as_float(q1.w));
    red[t] = a;
    __syncthreads();
    for (int off = 128; off > 0; off >>= 1) {
        if (t < off) red[t] += red[t + off];
        __syncthreads();
    }
    if (t == 0) {
        gsum[gid] = red[0];
        __threadfence();
        s_ticket = atomicAdd(fcnt, 1u);
    }
    __syncthreads();
    if (s_ticket != POISON + (unsigned)(LNGROUPS - 1)) return;

    __threadfence();
    red[t] = (t < LNGROUPS) ? gsum[t] : 0.0f;
    __syncthreads();
    for (int off = 128; off > 0; off >>= 1) {
        if (t < off) red[t] += red[t + off];
        __syncthreads();
    }
    if (t == 0) out[0] = red[0] * (1.0f / 65536.0f);
}

extern "C" void kernel_launch(void* const* d_in, const int* in_sizes, int n_in,
                              void* d_out, int out_size, void* d_ws, size_t ws_size,
                              hipStream_t stream)
{
    const float* P = (const float*)d_in[0];   // predict_pc [4,3,8192]
    const float* G = (const float*)d_in[1];   // gt_pc      [4,3,8192]
    float* out = (float*)d_out;               // scalar

    const size_t need64 = ((size_t)NPB * 64 * N_ + 256) * 4;   // ~16.8 MB
    const size_t need32 = ((size_t)NPB * 32 * N_ + 256) * 4;   // ~8.4 MB

    if (ws_size >= need64) {
        float* partial = (float*)d_ws;
        float* gsum2   = partial + (size_t)NPB * 64 * N_;
        chamfer_sweep_t<64><<<dim3(XBLKS, 64, NPB), THREADS, 0, stream>>>(P, G, partial);
        chamfer_reduce1_t<64><<<dim3(256), THREADS, 0, stream>>>(partial, gsum2);
        chamfer_final_kernel<<<dim3(1), THREADS, 0, stream>>>(gsum2, out);
    } else if (ws_size >= need32) {
        float* partial = (float*)d_ws;
        float* gsum2   = partial + (size_t)NPB * 32 * N_;
        chamfer_sweep_t<32><<<dim3(XBLKS, 32, NPB), THREADS, 0, stream>>>(P, G, partial);
        chamfer_reduce1_t<32><<<dim3(256), THREADS, 0, stream>>>(partial, gsum2);
        chamfer_final_kernel<<<dim3(1), THREADS, 0, stream>>>(gsum2, out);
    } else {
        unsigned* w    = (unsigned*)d_ws;
        unsigned* mins = w;                   // 65536 words
        unsigned* gcnt = w + 65536;           // 32 words
        unsigned* fcnt = w + 65600;           // 1 word
        float*    gsum = (float*)(w + 65664); // 32 words
        dim3 grid(LXBLKS, LYSPL, NPB);
        chamfer_fused_kernel<<<grid, THREADS, 0, stream>>>(P, G, mins, gcnt, fcnt, gsum, out);
    }
}

// Round 4
// 103.974 us; speedup vs baseline: 2.7984x; 2.7984x over previous
//
#include <hip/hip_runtime.h>
#include <math.h>

// Chamfer loss, B=4, C=3, Np=Ng=8192, fp32.
// Round 8: R3 minus the register clamp. R3's __launch_bounds__(256,8) forced
// VGPR 56->32, spilling the per-thread x-state; the inner loop re-read spills
// every iteration -> 474/487 MB scratch FETCH/WRITE, VALUBusy 13%, 250us.
// Default bounds restore R0's 56-VGPR no-spill allocation (56 rounds to the
// 64-reg HW granule => still 8 waves/SIMD possible). Structure otherwise
// unchanged from R3: YSPL=64 -> 2048 wgs full subscription, LDS ytile
// broadcast with RX=8 (32 packed-FMA issue cycles per 32B ds_read), plain
// coalesced partial stores (no atomics), stream-ordered reduce chain.
// ws gates: >=16.8MB primary (YSPL=64), >=8.4MB (YSPL=32), else R0 fallback.

#define B_       4
#define N_       8192
#define THREADS  256
#define RX       8
#define XB       (THREADS * RX)        // 2048 x-points per workgroup
#define XBLKS    (N_ / XB)             // 4
#define NPB      (2 * B_)              // 8 (pass,b) slabs

typedef float v2f __attribute__((ext_vector_type(2)));

__device__ __forceinline__ v2f pk_fma(v2f a, v2f b, v2f c) {
    v2f d;
    asm("v_pk_fma_f32 %0, %1, %2, %3" : "=v"(d) : "v"(a), "v"(b), "v"(c));
    return d;
}

// ---------------- primary path: sweep + reduce, atomic-free ----------------
// partial layout: [pb][ysplit][x:8192] floats.

template<int YSPL>
__global__ __launch_bounds__(THREADS)
void chamfer_sweep_t(const float* __restrict__ P, const float* __restrict__ G,
                     float* __restrict__ partial)
{
    constexpr int YCHUNK = N_ / YSPL;
    __shared__ float4 ytile[2 * (YCHUNK / 2)];   // pair-interleaved records

    const int t      = threadIdx.x;
    const int xblk   = blockIdx.x;     // 0..XBLKS-1
    const int ysplit = blockIdx.y;     // 0..YSPL-1
    const int bz     = blockIdx.z;     // 0..7
    const int pass   = bz >> 2;        // 0: X=predict, 1: X=gt
    const int b      = bz & 3;

    const float* Xb = (pass ? G : P) + (size_t)b * 3 * N_;
    const float* Yb = (pass ? P : G) + (size_t)b * 3 * N_;

    // Stage y-pairs: slot 2*jj = (gx0,gx1,gy0,gy1), 2*jj+1 = (gz0,gz1,g2_0,g2_1)
    const int ybase = ysplit * YCHUNK;
    if (t < YCHUNK / 2) {
        const int n0 = ybase + 2 * t;
        float2 x01 = *(const float2*)&Yb[n0];
        float2 y01 = *(const float2*)&Yb[N_ + n0];
        float2 z01 = *(const float2*)&Yb[2 * N_ + n0];
        float w0 = fmaf(x01.x, x01.x, fmaf(y01.x, y01.x, z01.x * z01.x));
        float w1 = fmaf(x01.y, x01.y, fmaf(y01.y, y01.y, z01.y * z01.y));
        ytile[2 * t]     = make_float4(x01.x, x01.y, y01.x, y01.y);
        ytile[2 * t + 1] = make_float4(z01.x, z01.y, w0, w1);
    }

    // RX x-points per thread; -2*coord duplicated into both float2 halves.
    const int xbase = xblk * XB;
    v2f m2x2[RX], m2y2[RX], m2z2[RX];
    float p2[RX], mn[RX];
#pragma unroll
    for (int r = 0; r < RX; ++r) {
        const int n = xbase + r * THREADS + t;
        float px = Xb[n];
        float py = Xb[N_ + n];
        float pz = Xb[2 * N_ + n];
        p2[r]   = fmaf(px, px, fmaf(py, py, pz * pz));
        float ax = -2.0f * px, ay = -2.0f * py, az = -2.0f * pz;
        m2x2[r] = (v2f){ax, ax};
        m2y2[r] = (v2f){ay, ay};
        m2z2[r] = (v2f){az, az};
        mn[r]   = 3.4e38f;
    }
    __syncthreads();

    // Sweep: per y-pair, per r: s = g2 - 2p.g for both y's (3 pk_fma),
    // then one min3 folds both halves into mn[r].
#pragma unroll 2
    for (int jj = 0; jj < YCHUNK / 2; ++jj) {
        float4 a4 = ytile[2 * jj];       // (gx0,gx1,gy0,gy1)
        float4 b4 = ytile[2 * jj + 1];   // (gz0,gz1,g2_0,g2_1)
        v2f gx2 = (v2f){a4.x, a4.y};
        v2f gy2 = (v2f){a4.z, a4.w};
        v2f gz2 = (v2f){b4.x, b4.y};
        v2f gw2 = (v2f){b4.z, b4.w};
#pragma unroll
        for (int r = 0; r < RX; ++r) {
            v2f s = pk_fma(m2z2[r], gz2, gw2);
            s = pk_fma(m2y2[r], gy2, s);
            s = pk_fma(m2x2[r], gx2, s);
            mn[r] = fminf(fminf(mn[r], s.x), s.y);   // -> v_min3_f32
        }
    }

    // Plain coalesced stores of clamped partial d2 (disjoint slots per wg).
    float* pout = partial + ((size_t)bz * YSPL + ysplit) * N_ + xbase;
#pragma unroll
    for (int r = 0; r < RX; ++r)
        pout[r * THREADS + t] = fmaxf(mn[r] + p2[r], 1e-12f);
}

// K2: per x-slot: min over YSPL partials, sqrt, block tree-sum.
template<int YSPL>
__global__ __launch_bounds__(THREADS)
void chamfer_reduce1_t(const float* __restrict__ partial,
                       float* __restrict__ gsum2)
{
    __shared__ float red[THREADS];
    const int g  = blockIdx.x * THREADS + threadIdx.x;   // [0, 65536)
    const int pb = g >> 13;
    const int x  = g & 8191;
    const float* p = partial + (size_t)pb * YSPL * N_ + x;
    float m = p[0];
#pragma unroll
    for (int ys = 1; ys < YSPL; ++ys)
        m = fminf(m, p[(size_t)ys * N_]);
    red[threadIdx.x] = sqrtf(m);
    __syncthreads();
    for (int off = 128; off > 0; off >>= 1) {
        if (threadIdx.x < off) red[threadIdx.x] += red[threadIdx.x + off];
        __syncthreads();
    }
    if (threadIdx.x == 0) gsum2[blockIdx.x] = red[0];
}

// K3: deterministic final sum of 256 block sums.
__global__ __launch_bounds__(THREADS)
void chamfer_final_kernel(const float* __restrict__ gsum2, float* __restrict__ out)
{
    __shared__ float red[THREADS];
    red[threadIdx.x] = gsum2[threadIdx.x];
    __syncthreads();
    for (int off = 128; off > 0; off >>= 1) {
        if (threadIdx.x < off) red[threadIdx.x] += red[threadIdx.x + off];
        __syncthreads();
    }
    if (threadIdx.x == 0) out[0] = red[0] * (1.0f / 65536.0f);   // denom = B*(Ng+Np)
}

// ---------------- fallback path (known-good R0, 257KB ws) ----------------
#define LRX      8
#define LXB      (THREADS * LRX)       // 2048
#define LXBLKS   (N_ / LXB)            // 4
#define LYSPL    32
#define LYCHUNK  (N_ / LYSPL)          // 256
#define LNGROUPS (2 * B_ * LXBLKS)     // 32
#define POISON   0xAAAAAAAAu

__global__ __launch_bounds__(THREADS)
void chamfer_fused_kernel(const float* __restrict__ P, const float* __restrict__ G,
                          unsigned* __restrict__ mins, unsigned* __restrict__ gcnt,
                          unsigned* __restrict__ fcnt, float* __restrict__ gsum,
                          float* __restrict__ out)
{
    __shared__ float4 ytile[2 * (LYCHUNK / 2)];
    __shared__ float red[THREADS];
    __shared__ unsigned s_ticket;

    const int t      = threadIdx.x;
    const int xblk   = blockIdx.x;
    const int ysplit = blockIdx.y;
    const int bz     = blockIdx.z;
    const int pass   = bz >> 2;
    const int b      = bz & 3;
    const int gid    = bz * LXBLKS + xblk;

    const float* Xb = (pass ? G : P) + (size_t)b * 3 * N_;
    const float* Yb = (pass ? P : G) + (size_t)b * 3 * N_;

    const int ybase = ysplit * LYCHUNK;
    if (t < LYCHUNK / 2) {
        const int n0 = ybase + 2 * t;
        float2 x01 = *(const float2*)&Yb[n0];
        float2 y01 = *(const float2*)&Yb[N_ + n0];
        float2 z01 = *(const float2*)&Yb[2 * N_ + n0];
        float w0 = fmaf(x01.x, x01.x, fmaf(y01.x, y01.x, z01.x * z01.x));
        float w1 = fmaf(x01.y, x01.y, fmaf(y01.y, y01.y, z01.y * z01.y));
        ytile[2 * t]     = make_float4(x01.x, x01.y, y01.x, y01.y);
        ytile[2 * t + 1] = make_float4(z01.x, z01.y, w0, w1);
    }

    const int xbase = xblk * LXB;
    v2f m2x2[LRX], m2y2[LRX], m2z2[LRX];
    float p2[LRX], mn[LRX];
#pragma unroll
    for (int r = 0; r < LRX; ++r) {
        const int n = xbase + r * THREADS + t;
        float px = Xb[n];
        float py = Xb[N_ + n];
        float pz = Xb[2 * N_ + n];
        p2[r]   = fmaf(px, px, fmaf(py, py, pz * pz));
        float ax = -2.0f * px, ay = -2.0f * py, az = -2.0f * pz;
        m2x2[r] = (v2f){ax, ax};
        m2y2[r] = (v2f){ay, ay};
        m2z2[r] = (v2f){az, az};
        mn[r]   = 3.4e38f;
    }
    __syncthreads();

#pragma unroll 2
    for (int jj = 0; jj < LYCHUNK / 2; ++jj) {
        float4 a4 = ytile[2 * jj];
        float4 b4 = ytile[2 * jj + 1];
        v2f gx2 = (v2f){a4.x, a4.y};
        v2f gy2 = (v2f){a4.z, a4.w};
        v2f gz2 = (v2f){b4.x, b4.y};
        v2f gw2 = (v2f){b4.z, b4.w};
#pragma unroll
        for (int r = 0; r < LRX; ++r) {
            v2f s = pk_fma(m2z2[r], gz2, gw2);
            s = pk_fma(m2y2[r], gy2, s);
            s = pk_fma(m2x2[r], gx2, s);
            mn[r] = fminf(fminf(mn[r], s.x), s.y);
        }
    }

    unsigned* mybase = mins + (size_t)(pass * B_ + b) * N_ + xbase;
#pragma unroll
    for (int r = 0; r < LRX; ++r) {
        float v = fmaxf(mn[r] + p2[r], 1e-12f);
        atomicMin(&mybase[r * THREADS + t], __float_as_uint(v));
    }

    __syncthreads();
    if (t == 0) {
        __threadfence();
        s_ticket = atomicAdd(&gcnt[gid], 1u);
    }
    __syncthreads();
    if (s_ticket != POISON + (unsigned)(LYSPL - 1)) return;

    __threadfence();
    const uint4* vmin = (const uint4*)(mins + (size_t)(pass * B_ + b) * N_ + xbase);
    uint4 q0 = vmin[t];
    uint4 q1 = vmin[THREADS + t];
    float a = sqrtf(__uint_as_float(q0.x)) + sqrtf(__uint_as_float(q0.y))
            + sqrtf(__uint_as_float(q0.z)) + sqrtf(__uint_as_float(q0.w))
            + sqrtf(__uint_as_float(q1.x)) + sqrtf(__uint_as_float(q1.y))
            + sqrtf(__uint_as_float(q1.z)) + sqrtf(__uint_as_float(q1.w));
    red[t] = a;
    __syncthreads();
    for (int off = 128; off > 0; off >>= 1) {
        if (t < off) red[t] += red[t + off];
        __syncthreads();
    }
    if (t == 0) {
        gsum[gid] = red[0];
        __threadfence();
        s_ticket = atomicAdd(fcnt, 1u);
    }
    __syncthreads();
    if (s_ticket != POISON + (unsigned)(LNGROUPS - 1)) return;

    __threadfence();
    red[t] = (t < LNGROUPS) ? gsum[t] : 0.0f;
    __syncthreads();
    for (int off = 128; off > 0; off >>= 1) {
        if (t < off) red[t] += red[t + off];
        __syncthreads();
    }
    if (t == 0) out[0] = red[0] * (1.0f / 65536.0f);
}

extern "C" void kernel_launch(void* const* d_in, const int* in_sizes, int n_in,
                              void* d_out, int out_size, void* d_ws, size_t ws_size,
                              hipStream_t stream)
{
    const float* P = (const float*)d_in[0];   // predict_pc [4,3,8192]
    const float* G = (const float*)d_in[1];   // gt_pc      [4,3,8192]
    float* out = (float*)d_out;               // scalar

    const size_t need64 = ((size_t)NPB * 64 * N_ + 256) * 4;   // ~16.8 MB
    const size_t need32 = ((size_t)NPB * 32 * N_ + 256) * 4;   // ~8.4 MB

    if (ws_size >= need64) {
        float* partial = (float*)d_ws;
        float* gsum2   = partial + (size_t)NPB * 64 * N_;
        chamfer_sweep_t<64><<<dim3(XBLKS, 64, NPB), THREADS, 0, stream>>>(P, G, partial);
        chamfer_reduce1_t<64><<<dim3(256), THREADS, 0, stream>>>(partial, gsum2);
        chamfer_final_kernel<<<dim3(1), THREADS, 0, stream>>>(gsum2, out);
    } else if (ws_size >= need32) {
        float* partial = (float*)d_ws;
        float* gsum2   = partial + (size_t)NPB * 32 * N_;
        chamfer_sweep_t<32><<<dim3(XBLKS, 32, NPB), THREADS, 0, stream>>>(P, G, partial);
        chamfer_reduce1_t<32><<<dim3(256), THREADS, 0, stream>>>(partial, gsum2);
        chamfer_final_kernel<<<dim3(1), THREADS, 0, stream>>>(gsum2, out);
    } else {
        unsigned* w    = (unsigned*)d_ws;
        unsigned* mins = w;                   // 65536 words
        unsigned* gcnt = w + 65536;           // 32 words
        unsigned* fcnt = w + 65600;           // 1 word
        float*    gsum = (float*)(w + 65664); // 32 words
        dim3 grid(LXBLKS, LYSPL, NPB);
        chamfer_fused_kernel<<<grid, THREADS, 0, stream>>>(P, G, mins, gcnt, fcnt, gsum, out);
    }
}

// Round 5
// 103.849 us; speedup vs baseline: 2.8018x; 1.0012x over previous
//
#include <hip/hip_runtime.h>
#include <math.h>

// Chamfer loss, B=4, C=3, Np=Ng=8192, fp32.
// Round 9: instruction-bloat + latency attack on the R4 sweep (46.2us,
// VALU busy-time 28.6us = 2.1x essential, occupancy 29% => per-wave duty 34%).
//  - ytile as v2f[]: MFMA-free inner loop wants v2f pairs; float4 staging
//    forced repack movs. Now fragments load directly into aligned pairs.
//  - explicit v_min3_f32 (1 inst per r-fold, no fminf-fusion gamble).
//  - explicit depth-2 software pipeline (prefetch jj+2, rotate registers,
//    8 v2f pad slots) so ~120cy ds_read latency hides under 128cy of pk_fma.
//  - p2[RX] dropped; recomputed at epilogue from the -2p regs (0.25*sum sq).
//  - reduce1: float4 loads, 128 wgs x 128 thr; final sums 128.
// Structure unchanged: YSPL=64 -> 2048 wgs, plain-store publish, stream-
// ordered reduce. ws gates: >=16.8MB (YSPL=64), >=8.4MB (YSPL=32), else R0
// fused fallback.

#define B_       4
#define N_       8192
#define THREADS  256
#define RX       8
#define XB       (THREADS * RX)        // 2048 x-points per workgroup
#define XBLKS    (N_ / XB)             // 4
#define NPB      (2 * B_)              // 8 (pass,b) slabs
#define RTHREADS 128

typedef float v2f __attribute__((ext_vector_type(2)));

__device__ __forceinline__ v2f pk_fma(v2f a, v2f b, v2f c) {
    v2f d;
    asm("v_pk_fma_f32 %0, %1, %2, %3" : "=v"(d) : "v"(a), "v"(b), "v"(c));
    return d;
}

__device__ __forceinline__ float min3f(float a, float b, float c) {
    float d;
    asm("v_min3_f32 %0, %1, %2, %3" : "=v"(d) : "v"(a), "v"(b), "v"(c));
    return d;
}

// ---------------- primary path: sweep + reduce, atomic-free ----------------
// partial layout: [pb][ysplit][x:8192] floats.

template<int YSPL>
__global__ __launch_bounds__(THREADS)
void chamfer_sweep_t(const float* __restrict__ P, const float* __restrict__ G,
                     float* __restrict__ partial)
{
    constexpr int YCHUNK = N_ / YSPL;
    constexpr int NJJ    = YCHUNK / 2;
    // 4 v2f per pair-record: {gx0,gx1},{gy0,gy1},{gz0,gz1},{g2_0,g2_1};
    // +8 pad v2f so the depth-2 prefetch stays in-bounds.
    __shared__ v2f ytile[4 * NJJ + 8];

    const int t      = threadIdx.x;
    const int xblk   = blockIdx.x;     // 0..XBLKS-1
    const int ysplit = blockIdx.y;     // 0..YSPL-1
    const int bz     = blockIdx.z;     // 0..7
    const int pass   = bz >> 2;        // 0: X=predict, 1: X=gt
    const int b      = bz & 3;

    const float* Xb = (pass ? G : P) + (size_t)b * 3 * N_;
    const float* Yb = (pass ? P : G) + (size_t)b * 3 * N_;

    // Stage y-pair records.
    const int ybase = ysplit * YCHUNK;
    if (t < NJJ) {
        const int n0 = ybase + 2 * t;
        float2 x01 = *(const float2*)&Yb[n0];
        float2 y01 = *(const float2*)&Yb[N_ + n0];
        float2 z01 = *(const float2*)&Yb[2 * N_ + n0];
        float w0 = fmaf(x01.x, x01.x, fmaf(y01.x, y01.x, z01.x * z01.x));
        float w1 = fmaf(x01.y, x01.y, fmaf(y01.y, y01.y, z01.y * z01.y));
        ytile[4 * t + 0] = (v2f){x01.x, x01.y};
        ytile[4 * t + 1] = (v2f){y01.x, y01.y};
        ytile[4 * t + 2] = (v2f){z01.x, z01.y};
        ytile[4 * t + 3] = (v2f){w0, w1};
    } else if (t < NJJ + 8) {
        ytile[4 * NJJ + (t - NJJ)] = (v2f){0.0f, 0.0f};   // pad
    }

    // RX x-points per thread; -2*coord duplicated into both halves.
    const int xbase = xblk * XB;
    v2f m2x2[RX], m2y2[RX], m2z2[RX];
    float mn[RX];
#pragma unroll
    for (int r = 0; r < RX; ++r) {
        const int n = xbase + r * THREADS + t;
        float px = Xb[n];
        float py = Xb[N_ + n];
        float pz = Xb[2 * N_ + n];
        float ax = -2.0f * px, ay = -2.0f * py, az = -2.0f * pz;
        m2x2[r] = (v2f){ax, ax};
        m2y2[r] = (v2f){ay, ay};
        m2z2[r] = (v2f){az, az};
        mn[r]   = 3.4e38f;
    }
    __syncthreads();

    // Depth-2 software pipeline: compute record jj from (cx0..cw0) while the
    // ds_read for jj+2 is in flight. Pad slots keep tail reads in-bounds.
    v2f cx0 = ytile[0], cy0 = ytile[1], cz0 = ytile[2], cw0 = ytile[3];
    v2f cx1 = ytile[4], cy1 = ytile[5], cz1 = ytile[6], cw1 = ytile[7];
#pragma unroll 2
    for (int jj = 0; jj < NJJ; ++jj) {
        const int pf = 4 * jj + 8;
        v2f nx = ytile[pf + 0];
        v2f ny = ytile[pf + 1];
        v2f nz = ytile[pf + 2];
        v2f nw = ytile[pf + 3];
#pragma unroll
        for (int r = 0; r < RX; ++r) {
            v2f s = pk_fma(m2z2[r], cz0, cw0);
            s = pk_fma(m2y2[r], cy0, s);
            s = pk_fma(m2x2[r], cx0, s);
            mn[r] = min3f(mn[r], s.x, s.y);
        }
        cx0 = cx1; cy0 = cy1; cz0 = cz1; cw0 = cw1;
        cx1 = nx;  cy1 = ny;  cz1 = nz;  cw1 = nw;
    }

    // Epilogue: p2 recomputed from the -2p registers (p = -a/2 => p2 = sumsq/4).
    float* pout = partial + ((size_t)bz * YSPL + ysplit) * N_ + xbase;
#pragma unroll
    for (int r = 0; r < RX; ++r) {
        float ax = m2x2[r].x, ay = m2y2[r].x, az = m2z2[r].x;
        float p2 = 0.25f * fmaf(ax, ax, fmaf(ay, ay, az * az));
        pout[r * THREADS + t] = fmaxf(mn[r] + p2, 1e-12f);
    }
}

// K2: per 4 x-slots: min over YSPL partials (float4), sqrt, block tree-sum.
template<int YSPL>
__global__ __launch_bounds__(RTHREADS)
void chamfer_reduce1_t(const float* __restrict__ partial,
                       float* __restrict__ gsum2)
{
    __shared__ float red[RTHREADS];
    const int g  = blockIdx.x * RTHREADS + threadIdx.x;  // [0, 16384)
    const int pb = g >> 11;                              // 0..7
    const int xq = g & 2047;                             // float4 index
    const float4* p = (const float4*)(partial + (size_t)pb * YSPL * N_) + xq;
    float4 m = p[0];
#pragma unroll
    for (int ys = 1; ys < YSPL; ++ys) {
        float4 v = p[(size_t)ys * (N_ / 4)];
        m.x = fminf(m.x, v.x); m.y = fminf(m.y, v.y);
        m.z = fminf(m.z, v.z); m.w = fminf(m.w, v.w);
    }
    red[threadIdx.x] = sqrtf(m.x) + sqrtf(m.y) + sqrtf(m.z) + sqrtf(m.w);
    __syncthreads();
    for (int off = RTHREADS / 2; off > 0; off >>= 1) {
        if (threadIdx.x < off) red[threadIdx.x] += red[threadIdx.x + off];
        __syncthreads();
    }
    if (threadIdx.x == 0) gsum2[blockIdx.x] = red[0];
}

// K3: deterministic final sum of 128 block sums.
__global__ __launch_bounds__(RTHREADS)
void chamfer_final_kernel(const float* __restrict__ gsum2, float* __restrict__ out)
{
    __shared__ float red[RTHREADS];
    red[threadIdx.x] = gsum2[threadIdx.x];
    __syncthreads();
    for (int off = RTHREADS / 2; off > 0; off >>= 1) {
        if (threadIdx.x < off) red[threadIdx.x] += red[threadIdx.x + off];
        __syncthreads();
    }
    if (threadIdx.x == 0) out[0] = red[0] * (1.0f / 65536.0f);   // denom = B*(Ng+Np)
}

// ---------------- fallback path (known-good R0, 257KB ws) ----------------
#define LRX      8
#define LXB      (THREADS * LRX)       // 2048
#define LXBLKS   (N_ / LXB)            // 4
#define LYSPL    32
#define LYCHUNK  (N_ / LYSPL)          // 256
#define LNGROUPS (2 * B_ * LXBLKS)     // 32
#define POISON   0xAAAAAAAAu

__global__ __launch_bounds__(THREADS)
void chamfer_fused_kernel(const float* __restrict__ P, const float* __restrict__ G,
                          unsigned* __restrict__ mins, unsigned* __restrict__ gcnt,
                          unsigned* __restrict__ fcnt, float* __restrict__ gsum,
                          float* __restrict__ out)
{
    __shared__ float4 ytile[2 * (LYCHUNK / 2)];
    __shared__ float red[THREADS];
    __shared__ unsigned s_ticket;

    const int t      = threadIdx.x;
    const int xblk   = blockIdx.x;
    const int ysplit = blockIdx.y;
    const int bz     = blockIdx.z;
    const int pass   = bz >> 2;
    const int b      = bz & 3;
    const int gid    = bz * LXBLKS + xblk;

    const float* Xb = (pass ? G : P) + (size_t)b * 3 * N_;
    const float* Yb = (pass ? P : G) + (size_t)b * 3 * N_;

    const int ybase = ysplit * LYCHUNK;
    if (t < LYCHUNK / 2) {
        const int n0 = ybase + 2 * t;
        float2 x01 = *(const float2*)&Yb[n0];
        float2 y01 = *(const float2*)&Yb[N_ + n0];
        float2 z01 = *(const float2*)&Yb[2 * N_ + n0];
        float w0 = fmaf(x01.x, x01.x, fmaf(y01.x, y01.x, z01.x * z01.x));
        float w1 = fmaf(x01.y, x01.y, fmaf(y01.y, y01.y, z01.y * z01.y));
        ytile[2 * t]     = make_float4(x01.x, x01.y, y01.x, y01.y);
        ytile[2 * t + 1] = make_float4(z01.x, z01.y, w0, w1);
    }

    const int xbase = xblk * LXB;
    v2f m2x2[LRX], m2y2[LRX], m2z2[LRX];
    float p2[LRX], mn[LRX];
#pragma unroll
    for (int r = 0; r < LRX; ++r) {
        const int n = xbase + r * THREADS + t;
        float px = Xb[n];
        float py = Xb[N_ + n];
        float pz = Xb[2 * N_ + n];
        p2[r]   = fmaf(px, px, fmaf(py, py, pz * pz));
        float ax = -2.0f * px, ay = -2.0f * py, az = -2.0f * pz;
        m2x2[r] = (v2f){ax, ax};
        m2y2[r] = (v2f){ay, ay};
        m2z2[r] = (v2f){az, az};
        mn[r]   = 3.4e38f;
    }
    __syncthreads();

#pragma unroll 2
    for (int jj = 0; jj < LYCHUNK / 2; ++jj) {
        float4 a4 = ytile[2 * jj];
        float4 b4 = ytile[2 * jj + 1];
        v2f gx2 = (v2f){a4.x, a4.y};
        v2f gy2 = (v2f){a4.z, a4.w};
        v2f gz2 = (v2f){b4.x, b4.y};
        v2f gw2 = (v2f){b4.z, b4.w};
#pragma unroll
        for (int r = 0; r < LRX; ++r) {
            v2f s = pk_fma(m2z2[r], gz2, gw2);
            s = pk_fma(m2y2[r], gy2, s);
            s = pk_fma(m2x2[r], gx2, s);
            mn[r] = fminf(fminf(mn[r], s.x), s.y);
        }
    }

    unsigned* mybase = mins + (size_t)(pass * B_ + b) * N_ + xbase;
#pragma unroll
    for (int r = 0; r < LRX; ++r) {
        float v = fmaxf(mn[r] + p2[r], 1e-12f);
        atomicMin(&mybase[r * THREADS + t], __float_as_uint(v));
    }

    __syncthreads();
    if (t == 0) {
        __threadfence();
        s_ticket = atomicAdd(&gcnt[gid], 1u);
    }
    __syncthreads();
    if (s_ticket != POISON + (unsigned)(LYSPL - 1)) return;

    __threadfence();
    const uint4* vmin = (const uint4*)(mins + (size_t)(pass * B_ + b) * N_ + xbase);
    uint4 q0 = vmin[t];
    uint4 q1 = vmin[THREADS + t];
    float a = sqrtf(__uint_as_float(q0.x)) + sqrtf(__uint_as_float(q0.y))
            + sqrtf(__uint_as_float(q0.z)) + sqrtf(__uint_as_float(q0.w))
            + sqrtf(__uint_as_float(q1.x)) + sqrtf(__uint_as_float(q1.y))
            + sqrtf(__uint_as_float(q1.z)) + sqrtf(__uint_as_float(q1.w));
    red[t] = a;
    __syncthreads();
    for (int off = 128; off > 0; off >>= 1) {
        if (t < off) red[t] += red[t + off];
        __syncthreads();
    }
    if (t == 0) {
        gsum[gid] = red[0];
        __threadfence();
        s_ticket = atomicAdd(fcnt, 1u);
    }
    __syncthreads();
    if (s_ticket != POISON + (unsigned)(LNGROUPS - 1)) return;

    __threadfence();
    red[t] = (t < LNGROUPS) ? gsum[t] : 0.0f;
    __syncthreads();
    for (int off = 128; off > 0; off >>= 1) {
        if (t < off) red[t] += red[t + off];
        __syncthreads();
    }
    if (t == 0) out[0] = red[0] * (1.0f / 65536.0f);
}

extern "C" void kernel_launch(void* const* d_in, const int* in_sizes, int n_in,
                              void* d_out, int out_size, void* d_ws, size_t ws_size,
                              hipStream_t stream)
{
    const float* P = (const float*)d_in[0];   // predict_pc [4,3,8192]
    const float* G = (const float*)d_in[1];   // gt_pc      [4,3,8192]
    float* out = (float*)d_out;               // scalar

    const size_t need64 = ((size_t)NPB * 64 * N_ + 256) * 4;   // ~16.8 MB
    const size_t need32 = ((size_t)NPB * 32 * N_ + 256) * 4;   // ~8.4 MB

    if (ws_size >= need64) {
        float* partial = (float*)d_ws;
        float* gsum2   = partial + (size_t)NPB * 64 * N_;
        chamfer_sweep_t<64><<<dim3(XBLKS, 64, NPB), THREADS, 0, stream>>>(P, G, partial);
        chamfer_reduce1_t<64><<<dim3(128), RTHREADS, 0, stream>>>(partial, gsum2);
        chamfer_final_kernel<<<dim3(1), RTHREADS, 0, stream>>>(gsum2, out);
    } else if (ws_size >= need32) {
        float* partial = (float*)d_ws;
        float* gsum2   = partial + (size_t)NPB * 32 * N_;
        chamfer_sweep_t<32><<<dim3(XBLKS, 32, NPB), THREADS, 0, stream>>>(P, G, partial);
        chamfer_reduce1_t<32><<<dim3(128), RTHREADS, 0, stream>>>(partial, gsum2);
        chamfer_final_kernel<<<dim3(1), RTHREADS, 0, stream>>>(gsum2, out);
    } else {
        unsigned* w    = (unsigned*)d_ws;
        unsigned* mins = w;                   // 65536 words
        unsigned* gcnt = w + 65536;           // 32 words
        unsigned* fcnt = w + 65600;           // 1 word
        float*    gsum = (float*)(w + 65664); // 32 words
        dim3 grid(LXBLKS, LYSPL, NPB);
        chamfer_fused_kernel<<<grid, THREADS, 0, stream>>>(P, G, mins, gcnt, fcnt, gsum, out);
    }
}